// Round 16
// baseline (149.699 us; speedup 1.0000x reference)
//
#include <hip/hip_runtime.h>
#include <stdint.h>

typedef unsigned short u16;
typedef __attribute__((ext_vector_type(8))) short short8;
typedef __attribute__((ext_vector_type(4))) float f32x4;
typedef __attribute__((ext_vector_type(4))) unsigned short u16x4;
typedef __attribute__((ext_vector_type(4))) unsigned int u32x4;

#define DEVI __device__ __forceinline__

DEVI u16 f2bf(float f) {
  uint32_t u = __builtin_bit_cast(uint32_t, f);
  u += 0x7fffu + ((u >> 16) & 1u);
  return (u16)(u >> 16);
}

DEVI float bf2f(u16 u) {
  uint32_t v = ((uint32_t)u) << 16;
  return __builtin_bit_cast(float, v);
}

DEVI uint32_t cvt_pk_bf16(float lo, float hi) {
  uint32_t r;
  asm("v_cvt_pk_bf16_f32 %0, %1, %2" : "=v"(r) : "v"(lo), "v"(hi));
  return r;
}

DEVI void gload_lds16(const void* g, void* l) {
  __builtin_amdgcn_global_load_lds(
      (const __attribute__((address_space(1))) void*)g,
      (__attribute__((address_space(3))) void*)(uint32_t)(uintptr_t)l,
      16, 0, 0);
}

// ---------------- merged convert: A_cat, W_cat, Wp in one sweep ----------------
__global__ void cvt_all(const float* __restrict__ x, const float* __restrict__ dte,
                        const float* __restrict__ Wqkv, const float* __restrict__ Wdt,
                        const float* __restrict__ Wproj,
                        u16* __restrict__ A_cat, u16* __restrict__ W_cat,
                        u16* __restrict__ Wp) {
  const long T0 = (long)4096 * 2048 / 4;
  const long T1 = (long)3072 * 2048 / 4;
  const long T2 = (long)1024 * 1024 / 4;
  for (long v = (long)blockIdx.x * 256 + threadIdx.x; v < T0 + T1 + T2;
       v += (long)gridDim.x * 256) {
    const float* src;
    u16* dst;
    if (v < T0) {
      const long i = v * 4;
      const long row = i >> 11, c = i & 2047;
      src = (c < 1024) ? (x + row * 1024 + c) : (dte + row * 1024 + (c - 1024));
      dst = A_cat + i;
    } else if (v < T0 + T1) {
      const long i = (v - T0) * 4;
      const long row = i >> 11, c = i & 2047;
      src = (c < 1024) ? (Wqkv + row * 1024 + c) : (Wdt + row * 1024 + (c - 1024));
      dst = W_cat + i;
    } else {
      const long i = (v - T0 - T1) * 4;
      src = Wproj + i;
      dst = Wp + i;
    }
    const float4 f = *(const float4*)src;
    u16x4 o = {f2bf(f.x), f2bf(f.y), f2bf(f.z), f2bf(f.w)};
    *(u16x4*)dst = o;
  }
}

// ------ bf16 GEMM 64x128 tile (m97 schedule + pair-row swizzle), fp32 out ------
__global__ __launch_bounds__(256, 2)
void gemm_bt64(const u16* __restrict__ A, const u16* __restrict__ B,
               float* __restrict__ C, const float* __restrict__ bias1,
               int M, int N, int K) {
  __shared__ u16 As[64 * 32];
  __shared__ u16 Bs[128 * 32];
  const int t = threadIdx.x;
  const int w = t >> 6, l = t & 63;
  const int l15 = l & 15, lg = l >> 4;
  const int bm = blockIdx.x, bn = blockIdx.y;
  const int wr = (w >> 1) * 32, wc = (w & 1) * 64;
  f32x4 acc[2][4] = {};
  const int su = (l & 7) ^ (l >> 3);
  const int rsub = 2 * (l >> 3) + (su >> 2);
  const int sg = su & 3;
  const int sfr = (lg + 4 * (l15 & 1)) ^ (l15 >> 1);
  const int lh = l15 >> 1;

  for (int kt = 0; kt < (K >> 5); ++kt) {
    {
      const int r = w * 16 + rsub;
      gload_lds16(A + (long)(bm * 64 + r) * K + kt * 32 + sg * 8,
                  (char*)As + (w * 8) * 128);
    }
#pragma unroll
    for (int i = 0; i < 2; ++i) {
      const int r = i * 64 + w * 16 + rsub;
      gload_lds16(B + (long)(bn * 128 + r) * K + kt * 32 + sg * 8,
                  (char*)Bs + (i * 32 + w * 8) * 128);
    }
    __syncthreads();
    short8 af[2], bfr[4];
#pragma unroll
    for (int m = 0; m < 2; ++m)
      af[m] = *(const short8*)&As[((w >> 1) * 16 + m * 8 + lh) * 64 + sfr * 8];
#pragma unroll
    for (int n = 0; n < 4; ++n)
      bfr[n] = *(const short8*)&Bs[((w & 1) * 32 + n * 8 + lh) * 64 + sfr * 8];
#pragma unroll
    for (int m = 0; m < 2; ++m)
#pragma unroll
      for (int n = 0; n < 4; ++n)
        acc[m][n] = __builtin_amdgcn_mfma_f32_16x16x32_bf16(af[m], bfr[n], acc[m][n], 0, 0, 0);
    __syncthreads();
  }
#pragma unroll
  for (int m = 0; m < 2; ++m) {
    const int row0 = bm * 64 + wr + m * 16 + lg * 4;
#pragma unroll
    for (int n = 0; n < 4; ++n) {
      const int col = bn * 128 + wc + n * 16 + l15;
      const float bia = bias1 ? bias1[col] : 0.f;
#pragma unroll
      for (int r = 0; r < 4; ++r)
        C[(long)(row0 + r) * N + col] = acc[m][n][r] + bia;
    }
  }
}

// ------ bf16 GEMM 128^2 (m97 schedule + swizzle), bf16 out — QKV+dt GEMM ------
__global__ __launch_bounds__(256, 2)
void gemm_bt_b16(const u16* __restrict__ A, const u16* __restrict__ B,
                 u16* __restrict__ C, const float* __restrict__ bias1,
                 const float* __restrict__ bias2, int M, int N, int K) {
  __shared__ u16 As[128 * 32];
  __shared__ u16 Bs[128 * 32];
  const int t = threadIdx.x;
  const int w = t >> 6, l = t & 63;
  const int l15 = l & 15, lg = l >> 4;
  const int bm = blockIdx.x, bn = blockIdx.y;
  const int wr = (w >> 1) * 64, wc = (w & 1) * 64;
  const int wrh = (w >> 1) * 32, wch = (w & 1) * 32;
  f32x4 acc[4][4] = {};
  const int su = (l & 7) ^ (l >> 3);
  const int rsub = 2 * (l >> 3) + (su >> 2);
  const int sg = su & 3;
  const int sfr = (lg + 4 * (l15 & 1)) ^ (l15 >> 1);
  const int lh = l15 >> 1;

  for (int kt = 0; kt < (K >> 5); ++kt) {
#pragma unroll
    for (int i = 0; i < 2; ++i) {
      const int r = i * 64 + w * 16 + rsub;
      gload_lds16(A + (long)(bm * 128 + r) * K + kt * 32 + sg * 8,
                  (char*)As + (i * 32 + w * 8) * 128);
      gload_lds16(B + (long)(bn * 128 + r) * K + kt * 32 + sg * 8,
                  (char*)Bs + (i * 32 + w * 8) * 128);
    }
    __syncthreads();
    short8 af[4], bfr[4];
#pragma unroll
    for (int m = 0; m < 4; ++m)
      af[m] = *(const short8*)&As[(wrh + m * 8 + lh) * 64 + sfr * 8];
#pragma unroll
    for (int n = 0; n < 4; ++n)
      bfr[n] = *(const short8*)&Bs[(wch + n * 8 + lh) * 64 + sfr * 8];
#pragma unroll
    for (int m = 0; m < 4; ++m)
#pragma unroll
      for (int n = 0; n < 4; ++n)
        acc[m][n] = __builtin_amdgcn_mfma_f32_16x16x32_bf16(af[m], bfr[n], acc[m][n], 0, 0, 0);
    __syncthreads();
  }
#pragma unroll
  for (int m = 0; m < 4; ++m) {
    const int row0 = bm * 128 + wr + m * 16 + lg * 4;
#pragma unroll
    for (int n = 0; n < 4; ++n) {
      const int col = bn * 128 + wc + n * 16 + l15;
      float bia = 0.f;
      if (bias1) bia += bias1[col];
      if (bias2) bia += bias2[col];
#pragma unroll
      for (int r = 0; r < 4; ++r)
        C[(long)(row0 + r) * N + col] = f2bf(acc[m][n][r] + bia);
    }
  }
}

// ---- fuse v3 (vectorized): split qkv, vres mix, LN(q,k), RoPE ----
// Lane = one 8-element chunk of one head: 8 lanes cover 64 d.
// short8/float4 loads, 8-lane shfl LN, shfl_xor(4) RoPE partner, short8 stores.
__global__ __launch_bounds__(256)
void fuse_qkv3(const u16* __restrict__ qkv, const float* __restrict__ vres,
               const float* __restrict__ rope,
               const float* __restrict__ qg, const float* __restrict__ qb,
               const float* __restrict__ kg, const float* __restrict__ kb,
               const float* __restrict__ pl1, const float* __restrict__ pl2,
               u16* __restrict__ Q, u16* __restrict__ Ksw, u16* __restrict__ VTsw) {
  __shared__ u16 Vl[64][72];
  const int t = threadIdx.x, w = t >> 6, l = t & 63;
  const int lg8 = l >> 3;   // token subgroup within wave
  const int c8 = l & 7;     // 8-el chunk within head
  const int dh0 = c8 * 8;
  const int bh = blockIdx.x, ntile = blockIdx.y;
  const int b = bh >> 4, h = bh & 15, n0 = ntile * 64;
  const float l1 = pl1[0], l2 = pl2[0];
  const float sgn = (c8 < 4) ? -1.f : 1.f;
  float gqv[8], bqv[8], gkv[8], bkv[8];
#pragma unroll
  for (int u = 0; u < 8; ++u) {
    gqv[u] = qg[dh0 + u];
    bqv[u] = qb[dh0 + u];
    gkv[u] = kg[dh0 + u];
    bkv[u] = kb[dh0 + u];
  }

#pragma unroll
  for (int it = 0; it < 2; ++it) {
    const int tl = it * 32 + w * 8 + lg8;
    const int n = n0 + tl;
    const long base = ((long)(b * 1024 + n)) * 3072 + h * 64 + dh0;
    const short8 qv = *(const short8*)&qkv[base];
    const short8 kv = *(const short8*)&qkv[base + 1024];
    const short8 vv = *(const short8*)&qkv[base + 2048];
    const long vb = ((long)(bh * 1024 + n)) * 64 + dh0;
    const float4 vr0 = *(const float4*)&vres[vb];
    const float4 vr1 = *(const float4*)&vres[vb + 4];
    float qf[8], kf[8], vf[8];
#pragma unroll
    for (int u = 0; u < 8; ++u) {
      qf[u] = bf2f((u16)qv[u]);
      kf[u] = bf2f((u16)kv[u]);
      vf[u] = bf2f((u16)vv[u]);
    }
    // LN q
    float s = 0.f;
#pragma unroll
    for (int u = 0; u < 8; ++u) s += qf[u];
    s += __shfl_xor(s, 1); s += __shfl_xor(s, 2); s += __shfl_xor(s, 4);
    const float mq = s * (1.f / 64.f);
    float vsq = 0.f;
#pragma unroll
    for (int u = 0; u < 8; ++u) { qf[u] -= mq; vsq += qf[u] * qf[u]; }
    vsq += __shfl_xor(vsq, 1); vsq += __shfl_xor(vsq, 2); vsq += __shfl_xor(vsq, 4);
    const float rq = 1.f / sqrtf(vsq * (1.f / 64.f) + 1e-5f);
    // LN k
    float s2 = 0.f;
#pragma unroll
    for (int u = 0; u < 8; ++u) s2 += kf[u];
    s2 += __shfl_xor(s2, 1); s2 += __shfl_xor(s2, 2); s2 += __shfl_xor(s2, 4);
    const float mk = s2 * (1.f / 64.f);
    float vsk = 0.f;
#pragma unroll
    for (int u = 0; u < 8; ++u) { kf[u] -= mk; vsk += kf[u] * kf[u]; }
    vsk += __shfl_xor(vsk, 1); vsk += __shfl_xor(vsk, 2); vsk += __shfl_xor(vsk, 4);
    const float rk = 1.f / sqrtf(vsk * (1.f / 64.f) + 1e-5f);
    float qn[8], kn[8];
#pragma unroll
    for (int u = 0; u < 8; ++u) {
      qn[u] = qf[u] * rq * gqv[u] + bqv[u];
      kn[u] = kf[u] * rk * gkv[u] + bkv[u];
    }
    // RoPE: partner chunk lives in lane l^4 (dh^32)
    float qp[8], kp[8];
#pragma unroll
    for (int u = 0; u < 8; ++u) {
      qp[u] = __shfl_xor(qn[u], 4);
      kp[u] = __shfl_xor(kn[u], 4);
    }
    const float4 sn0 = *(const float4*)&rope[n * 128 + dh0];
    const float4 sn1 = *(const float4*)&rope[n * 128 + dh0 + 4];
    const float4 cs0 = *(const float4*)&rope[n * 128 + 64 + dh0];
    const float4 cs1 = *(const float4*)&rope[n * 128 + 64 + dh0 + 4];
    const float sn[8] = {sn0.x, sn0.y, sn0.z, sn0.w, sn1.x, sn1.y, sn1.z, sn1.w};
    const float cs[8] = {cs0.x, cs0.y, cs0.z, cs0.w, cs1.x, cs1.y, cs1.z, cs1.w};
    short8 qo, ko, vo;
#pragma unroll
    for (int u = 0; u < 8; ++u) {
      qo[u] = (short)f2bf(qn[u] * cs[u] + sgn * qp[u] * sn[u]);
      ko[u] = (short)f2bf(kn[u] * cs[u] + sgn * kp[u] * sn[u]);
    }
    const float vr[8] = {vr0.x, vr0.y, vr0.z, vr0.w, vr1.x, vr1.y, vr1.z, vr1.w};
#pragma unroll
    for (int u = 0; u < 8; ++u) vo[u] = (short)f2bf(l1 * vf[u] + l2 * vr[u]);
    const long obase = (long)bh * 65536 + (long)n * 64;
    *(short8*)&Q[obase + dh0] = qo;
    *(short8*)&Ksw[obase + ((c8 ^ (n & 7)) * 8)] = ko;
    *(short8*)&Vl[tl][dh0] = vo;
  }
  __syncthreads();
  // transpose-write V^T (chunk-swizzled per 64-n tile) — proven fuse_qkv2 tail
#pragma unroll
  for (int i = 0; i < 2; ++i) {
    const int task = i * 256 + t;
    const int dd = task >> 3, cc = task & 7;
    short8 o;
#pragma unroll
    for (int u = 0; u < 8; ++u) o[u] = (short)Vl[cc * 8 + u][dd];
    *(short8*)&VTsw[((long)(bh * 64 + dd)) * 1024 + n0 + ((cc ^ (dd & 7)) * 8)] = o;
  }
}

// -------- flash attention fwd v8: in-register P + KVBLK=128 (round-11) --------
__global__ __launch_bounds__(256, 4)
void attn_fwd8(const u16* __restrict__ Q, const u16* __restrict__ Ksw,
               const u16* __restrict__ VTsw, u16* __restrict__ Out) {
  __shared__ u16 Kl[128 * 64];
  __shared__ u16 Vl[64 * 128];
  const int t = threadIdx.x, w = t >> 6, l = t & 63;
  const int l15 = l & 15, lg = l >> 4;
  const int x7 = l15 & 7;
  const int bh = blockIdx.x, q0 = blockIdx.y * 64;
  const long bo = (long)bh * 65536;
  const bool hihalf = (l & 16) != 0;

  const int qrow = q0 + w * 16 + l15;
  short8 qf[2];
#pragma unroll
  for (int ks = 0; ks < 2; ++ks)
    qf[ks] = *(const short8*)&Q[bo + (long)qrow * 64 + ks * 32 + lg * 8];

  f32x4 acc[4] = {};
  float m_run = -1e30f, l_run = 0.f;

  for (int kb = 0; kb < 8; ++kb) {
    const int kvb = kb * 128;
#pragma unroll
    for (int i = 0; i < 4; ++i) {
      const int idx = i * 256 + t;
      const int krow = idx >> 3, kseg = idx & 7;
      gload_lds16(Ksw + bo + (long)(kvb + krow) * 64 + kseg * 8, (char*)Kl + idx * 16);
      const int vd = idx >> 4, vc = idx & 15;
      gload_lds16(VTsw + bo + (long)vd * 1024 + kvb + vc * 8,
                  (char*)Vl + vd * 256 + vc * 16);
    }
    __syncthreads();
#pragma unroll
    for (int tb = 0; tb < 2; ++tb) {
      f32x4 p[4];
#pragma unroll
      for (int mt = 0; mt < 4; ++mt) {
        f32x4 ps = {};
#pragma unroll
        for (int ks = 0; ks < 2; ++ks) {
          const short8 kf = *(const short8*)&Kl[(tb * 64 + mt * 16 + l15) * 64 +
                                                (((ks * 4 + lg) ^ x7) * 8)];
          ps = __builtin_amdgcn_mfma_f32_16x16x32_bf16(kf, qf[ks], ps, 0, 0, 0);
        }
        p[mt] = ps;
      }
      float mx = p[0][0];
#pragma unroll
      for (int mt = 0; mt < 4; ++mt)
#pragma unroll
        for (int r = 0; r < 4; ++r) mx = fmaxf(mx, p[mt][r]);
      mx = fmaxf(mx, __shfl_xor(mx, 16));
      mx = fmaxf(mx, __shfl_xor(mx, 32));
      const float mnew = fmaxf(m_run, mx * 0.125f);
      const float alpha = __expf(m_run - mnew);
      m_run = mnew;
      float sum = 0.f;
#pragma unroll
      for (int mt = 0; mt < 4; ++mt)
#pragma unroll
        for (int r = 0; r < 4; ++r) {
          const float e = __expf(p[mt][r] * 0.125f - mnew);
          p[mt][r] = e;
          sum += e;
        }
      sum += __shfl_xor(sum, 16);
      sum += __shfl_xor(sum, 32);
      l_run = l_run * alpha + sum;
      uint32_t u0[4], u1[4];
#pragma unroll
      for (int mt = 0; mt < 4; ++mt) {
        u0[mt] = cvt_pk_bf16(p[mt][0], p[mt][1]);
        u1[mt] = cvt_pk_bf16(p[mt][2], p[mt][3]);
      }
#pragma unroll
      for (int mt = 0; mt < 4; ++mt)
#pragma unroll
        for (int r = 0; r < 4; ++r) acc[mt][r] *= alpha;
#pragma unroll
      for (int ks = 0; ks < 2; ++ks) {
        uint32_t X0 = u0[2 * ks], Y0 = u0[2 * ks + 1];
        asm("v_permlane32_swap_b32 %0, %1" : "+v"(X0), "+v"(Y0));
        uint32_t X1 = u1[2 * ks], Y1 = u1[2 * ks + 1];
        asm("v_permlane32_swap_b32 %0, %1" : "+v"(X1), "+v"(Y1));
        const uint32_t Xs0 = (uint32_t)__shfl_xor((int)X0, 16);
        const uint32_t Ys0 = (uint32_t)__shfl_xor((int)Y0, 16);
        const uint32_t Xs1 = (uint32_t)__shfl_xor((int)X1, 16);
        const uint32_t Ys1 = (uint32_t)__shfl_xor((int)Y1, 16);
        u32x4 pv;
        pv[0] = hihalf ? Ys0 : X0;
        pv[1] = hihalf ? Ys1 : X1;
        pv[2] = hihalf ? Y0 : Xs0;
        pv[3] = hihalf ? Y1 : Xs1;
        const short8 pf = __builtin_bit_cast(short8, pv);
#pragma unroll
        for (int mt = 0; mt < 4; ++mt) {
          const short8 vf = *(const short8*)&Vl[(mt * 16 + l15) * 128 + tb * 64 +
                                                (((ks * 4 + lg) ^ x7) * 8)];
          acc[mt] = __builtin_amdgcn_mfma_f32_16x16x32_bf16(vf, pf, acc[mt], 0, 0, 0);
        }
      }
    }
    __syncthreads();
  }
  const int b = bh >> 4, h = bh & 15;
  const float inv = 1.f / l_run;
  const long obase = ((long)(b * 1024 + qrow)) * 1024 + h * 64;
#pragma unroll
  for (int mt = 0; mt < 4; ++mt) {
    const long o = obase + mt * 16 + lg * 4;
    *(uint32_t*)&Out[o] = cvt_pk_bf16(acc[mt][0] * inv, acc[mt][1] * inv);
    *(uint32_t*)&Out[o + 2] = cvt_pk_bf16(acc[mt][2] * inv, acc[mt][3] * inv);
  }
}

extern "C" void kernel_launch(void* const* d_in, const int* in_sizes, int n_in,
                              void* d_out, int out_size, void* d_ws, size_t ws_size,
                              hipStream_t stream) {
  const float* x     = (const float*)d_in[0];
  const float* rope  = (const float*)d_in[1];
  const float* dte   = (const float*)d_in[2];
  const float* vres  = (const float*)d_in[3];
  const float* Wqkv  = (const float*)d_in[4];
  const float* bqkv  = (const float*)d_in[5];
  const float* Wdt   = (const float*)d_in[6];
  const float* bdt   = (const float*)d_in[7];
  const float* qn_g  = (const float*)d_in[8];
  const float* qn_b  = (const float*)d_in[9];
  const float* kn_g  = (const float*)d_in[10];
  const float* kn_b  = (const float*)d_in[11];
  const float* l1    = (const float*)d_in[12];
  const float* l2    = (const float*)d_in[13];
  const float* Wproj = (const float*)d_in[14];
  const float* bproj = (const float*)d_in[15];
  float* out = (float*)d_out;

  char* ws = (char*)d_ws;
  u16*   A_cat = (u16*)(ws);                    // [4096,2048] bf16
  u16*   W_cat = (u16*)(ws + 16777216);         // [3072,2048] bf16
  u16*   Wp    = (u16*)(ws + 29360128);         // [1024,1024] bf16
  u16*   qkvb  = (u16*)(ws + 31457280);         // [4096,3072] bf16
  u16*   Qb    = (u16*)(ws + 56623104);         // [64,1024,64] bf16
  u16*   Ksw   = (u16*)(ws + 65011712);         // swizzled K
  u16*   VTsw  = (u16*)(ws + 73400320);         // swizzled V^T
  u16*   AO    = (u16*)(ws + 81788928);         // [4096,1024] bf16
  // total ws usage: 90,177,536 bytes

  cvt_all<<<2048, 256, 0, stream>>>(x, dte, Wqkv, Wdt, Wproj, A_cat, W_cat, Wp);
  gemm_bt_b16<<<dim3(32, 24), 256, 0, stream>>>(A_cat, W_cat, qkvb, bqkv, bdt,
                                                4096, 3072, 2048);
  fuse_qkv3<<<dim3(64, 16), 256, 0, stream>>>(qkvb, vres, rope, qn_g, qn_b, kn_g, kn_b,
                                              l1, l2, Qb, Ksw, VTsw);
  attn_fwd8<<<dim3(64, 16), 256, 0, stream>>>(Qb, Ksw, VTsw, AO);
  gemm_bt64<<<dim3(64, 8), 256, 0, stream>>>(AO, Wp, out, bproj, 4096, 1024, 1024);
}

// Round 17
// 146.179 us; speedup vs baseline: 1.0241x; 1.0241x over previous
//
#include <hip/hip_runtime.h>
#include <stdint.h>

typedef unsigned short u16;
typedef __attribute__((ext_vector_type(8))) short short8;
typedef __attribute__((ext_vector_type(4))) float f32x4;
typedef __attribute__((ext_vector_type(4))) unsigned short u16x4;
typedef __attribute__((ext_vector_type(4))) unsigned int u32x4;

#define DEVI __device__ __forceinline__

DEVI u16 f2bf(float f) {
  uint32_t u = __builtin_bit_cast(uint32_t, f);
  u += 0x7fffu + ((u >> 16) & 1u);
  return (u16)(u >> 16);
}

DEVI float bf2f(u16 u) {
  uint32_t v = ((uint32_t)u) << 16;
  return __builtin_bit_cast(float, v);
}

DEVI uint32_t cvt_pk_bf16(float lo, float hi) {
  uint32_t r;
  asm("v_cvt_pk_bf16_f32 %0, %1, %2" : "=v"(r) : "v"(lo), "v"(hi));
  return r;
}

DEVI void gload_lds16(const void* g, void* l) {
  __builtin_amdgcn_global_load_lds(
      (const __attribute__((address_space(1))) void*)g,
      (__attribute__((address_space(3))) void*)(uint32_t)(uintptr_t)l,
      16, 0, 0);
}

// ---------------- merged convert: A_cat, W_cat, Wp in one sweep ----------------
__global__ void cvt_all(const float* __restrict__ x, const float* __restrict__ dte,
                        const float* __restrict__ Wqkv, const float* __restrict__ Wdt,
                        const float* __restrict__ Wproj,
                        u16* __restrict__ A_cat, u16* __restrict__ W_cat,
                        u16* __restrict__ Wp) {
  const long T0 = (long)4096 * 2048 / 4;
  const long T1 = (long)3072 * 2048 / 4;
  const long T2 = (long)1024 * 1024 / 4;
  for (long v = (long)blockIdx.x * 256 + threadIdx.x; v < T0 + T1 + T2;
       v += (long)gridDim.x * 256) {
    const float* src;
    u16* dst;
    if (v < T0) {
      const long i = v * 4;
      const long row = i >> 11, c = i & 2047;
      src = (c < 1024) ? (x + row * 1024 + c) : (dte + row * 1024 + (c - 1024));
      dst = A_cat + i;
    } else if (v < T0 + T1) {
      const long i = (v - T0) * 4;
      const long row = i >> 11, c = i & 2047;
      src = (c < 1024) ? (Wqkv + row * 1024 + c) : (Wdt + row * 1024 + (c - 1024));
      dst = W_cat + i;
    } else {
      const long i = (v - T0 - T1) * 4;
      src = Wproj + i;
      dst = Wp + i;
    }
    const float4 f = *(const float4*)src;
    u16x4 o = {f2bf(f.x), f2bf(f.y), f2bf(f.z), f2bf(f.w)};
    *(u16x4*)dst = o;
  }
}

// ------ bf16 GEMM 64x128 tile (m97 schedule + pair-row swizzle), fp32 out ------
__global__ __launch_bounds__(256, 2)
void gemm_bt64(const u16* __restrict__ A, const u16* __restrict__ B,
               float* __restrict__ C, const float* __restrict__ bias1,
               int M, int N, int K) {
  __shared__ u16 As[64 * 32];
  __shared__ u16 Bs[128 * 32];
  const int t = threadIdx.x;
  const int w = t >> 6, l = t & 63;
  const int l15 = l & 15, lg = l >> 4;
  const int bm = blockIdx.x, bn = blockIdx.y;
  const int wr = (w >> 1) * 32, wc = (w & 1) * 64;
  f32x4 acc[2][4] = {};
  const int su = (l & 7) ^ (l >> 3);
  const int rsub = 2 * (l >> 3) + (su >> 2);
  const int sg = su & 3;
  const int sfr = (lg + 4 * (l15 & 1)) ^ (l15 >> 1);
  const int lh = l15 >> 1;

  for (int kt = 0; kt < (K >> 5); ++kt) {
    {
      const int r = w * 16 + rsub;
      gload_lds16(A + (long)(bm * 64 + r) * K + kt * 32 + sg * 8,
                  (char*)As + (w * 8) * 128);
    }
#pragma unroll
    for (int i = 0; i < 2; ++i) {
      const int r = i * 64 + w * 16 + rsub;
      gload_lds16(B + (long)(bn * 128 + r) * K + kt * 32 + sg * 8,
                  (char*)Bs + (i * 32 + w * 8) * 128);
    }
    __syncthreads();
    short8 af[2], bfr[4];
#pragma unroll
    for (int m = 0; m < 2; ++m)
      af[m] = *(const short8*)&As[((w >> 1) * 16 + m * 8 + lh) * 64 + sfr * 8];
#pragma unroll
    for (int n = 0; n < 4; ++n)
      bfr[n] = *(const short8*)&Bs[((w & 1) * 32 + n * 8 + lh) * 64 + sfr * 8];
#pragma unroll
    for (int m = 0; m < 2; ++m)
#pragma unroll
      for (int n = 0; n < 4; ++n)
        acc[m][n] = __builtin_amdgcn_mfma_f32_16x16x32_bf16(af[m], bfr[n], acc[m][n], 0, 0, 0);
    __syncthreads();
  }
#pragma unroll
  for (int m = 0; m < 2; ++m) {
    const int row0 = bm * 64 + wr + m * 16 + lg * 4;
#pragma unroll
    for (int n = 0; n < 4; ++n) {
      const int col = bn * 128 + wc + n * 16 + l15;
      const float bia = bias1 ? bias1[col] : 0.f;
#pragma unroll
      for (int r = 0; r < 4; ++r)
        C[(long)(row0 + r) * N + col] = acc[m][n][r] + bia;
    }
  }
}

// ---- QKV GEMM (m97 schedule + swizzle) writing HEAD-MAJOR raw outputs --------
// Output: Qraw/Kraw/Vraw [bh=b*16+h][n][64] bf16 (bias included).
// sect = bn>>3 (0:q 1:k 2:v); head h = (bn&7)*2 + (wc>>6); d = n*16+l15.
__global__ __launch_bounds__(256, 2)
void gemm_qkv_hm(const u16* __restrict__ A, const u16* __restrict__ B,
                 const float* __restrict__ bias1, const float* __restrict__ bias2,
                 u16* __restrict__ Qraw, u16* __restrict__ Kraw,
                 u16* __restrict__ Vraw, int M, int N, int K) {
  __shared__ u16 As[128 * 32];
  __shared__ u16 Bs[128 * 32];
  const int t = threadIdx.x;
  const int w = t >> 6, l = t & 63;
  const int l15 = l & 15, lg = l >> 4;
  const int bm = blockIdx.x, bn = blockIdx.y;
  const int wr = (w >> 1) * 64, wc = (w & 1) * 64;
  const int wrh = (w >> 1) * 32, wch = (w & 1) * 32;
  f32x4 acc[4][4] = {};
  const int su = (l & 7) ^ (l >> 3);
  const int rsub = 2 * (l >> 3) + (su >> 2);
  const int sg = su & 3;
  const int sfr = (lg + 4 * (l15 & 1)) ^ (l15 >> 1);
  const int lh = l15 >> 1;

  for (int kt = 0; kt < (K >> 5); ++kt) {
#pragma unroll
    for (int i = 0; i < 2; ++i) {
      const int r = i * 64 + w * 16 + rsub;
      gload_lds16(A + (long)(bm * 128 + r) * K + kt * 32 + sg * 8,
                  (char*)As + (i * 32 + w * 8) * 128);
      gload_lds16(B + (long)(bn * 128 + r) * K + kt * 32 + sg * 8,
                  (char*)Bs + (i * 32 + w * 8) * 128);
    }
    __syncthreads();
    short8 af[4], bfr[4];
#pragma unroll
    for (int m = 0; m < 4; ++m)
      af[m] = *(const short8*)&As[(wrh + m * 8 + lh) * 64 + sfr * 8];
#pragma unroll
    for (int n = 0; n < 4; ++n)
      bfr[n] = *(const short8*)&Bs[(wch + n * 8 + lh) * 64 + sfr * 8];
#pragma unroll
    for (int m = 0; m < 4; ++m)
#pragma unroll
      for (int n = 0; n < 4; ++n)
        acc[m][n] = __builtin_amdgcn_mfma_f32_16x16x32_bf16(af[m], bfr[n], acc[m][n], 0, 0, 0);
    __syncthreads();
  }
  // head-major epilogue
  u16* Traw = (bn < 8) ? Qraw : (bn < 16) ? Kraw : Vraw;
  const int h = ((bn & 7) << 1) | (wc >> 6);
  const long tb = ((long)((bm >> 3) * 16 + h)) << 16;  // *65536
  const int nnbase = (bm & 7) * 128 + wr;
#pragma unroll
  for (int m = 0; m < 4; ++m) {
#pragma unroll
    for (int n = 0; n < 4; ++n) {
      const int col = bn * 128 + wc + n * 16 + l15;
      float bia = bias1[col] + bias2[col];
      const int d = n * 16 + l15;
#pragma unroll
      for (int r = 0; r < 4; ++r) {
        const int nn = nnbase + m * 16 + lg * 4 + r;
        Traw[tb + (long)nn * 64 + d] = f2bf(acc[m][n][r] + bia);
      }
    }
  }
}

// ---- fuse v4: head-major reads, in-register RoPE, cvt_pk packing ----
// Lane owns chunks d in [c4*8,+8) and [c4*8+32,+8) of ONE token (4 lanes/token,
// 16 tokens/wave). RoPE rotate-half partner is the other register: 0 shfls.
// LN over 4 lanes: 2 shfls per reduction.
__global__ __launch_bounds__(256)
void fuse_qkv4(const u16* __restrict__ Qraw, const u16* __restrict__ Kraw,
               const u16* __restrict__ Vraw, const float* __restrict__ vres,
               const float* __restrict__ rope,
               const float* __restrict__ qg, const float* __restrict__ qb,
               const float* __restrict__ kg, const float* __restrict__ kb,
               const float* __restrict__ pl1, const float* __restrict__ pl2,
               u16* __restrict__ Q, u16* __restrict__ Ksw, u16* __restrict__ VTsw) {
  __shared__ u16 Vl[64][72];
  const int t = threadIdx.x, w = t >> 6, l = t & 63;
  const int c4 = l & 3;
  const int tg = l >> 2;
  const int d0 = c4 * 8;
  const int bh = blockIdx.x, ntile = blockIdx.y;
  const int n0 = ntile * 64;
  const int tl = w * 16 + tg;
  const int n = n0 + tl;
  const long obase = (long)bh * 65536 + (long)n * 64;
  const int nx = n & 7;

  // rope factors (L2/L3-hot)
  float sn_lo[8], sn_hi[8], cs_lo[8], cs_hi[8];
  {
    const float4 a0 = *(const float4*)&rope[n * 128 + d0];
    const float4 a1 = *(const float4*)&rope[n * 128 + d0 + 4];
    const float4 b0 = *(const float4*)&rope[n * 128 + 32 + d0];
    const float4 b1 = *(const float4*)&rope[n * 128 + 32 + d0 + 4];
    const float4 c0 = *(const float4*)&rope[n * 128 + 64 + d0];
    const float4 c1 = *(const float4*)&rope[n * 128 + 64 + d0 + 4];
    const float4 e0 = *(const float4*)&rope[n * 128 + 96 + d0];
    const float4 e1 = *(const float4*)&rope[n * 128 + 96 + d0 + 4];
    sn_lo[0]=a0.x; sn_lo[1]=a0.y; sn_lo[2]=a0.z; sn_lo[3]=a0.w;
    sn_lo[4]=a1.x; sn_lo[5]=a1.y; sn_lo[6]=a1.z; sn_lo[7]=a1.w;
    sn_hi[0]=b0.x; sn_hi[1]=b0.y; sn_hi[2]=b0.z; sn_hi[3]=b0.w;
    sn_hi[4]=b1.x; sn_hi[5]=b1.y; sn_hi[6]=b1.z; sn_hi[7]=b1.w;
    cs_lo[0]=c0.x; cs_lo[1]=c0.y; cs_lo[2]=c0.z; cs_lo[3]=c0.w;
    cs_lo[4]=c1.x; cs_lo[5]=c1.y; cs_lo[6]=c1.z; cs_lo[7]=c1.w;
    cs_hi[0]=e0.x; cs_hi[1]=e0.y; cs_hi[2]=e0.z; cs_hi[3]=e0.w;
    cs_hi[4]=e1.x; cs_hi[5]=e1.y; cs_hi[6]=e1.z; cs_hi[7]=e1.w;
  }

  // ---- Q phase ----
  {
    const short8 xlo = *(const short8*)&Qraw[obase + d0];
    const short8 xhi = *(const short8*)&Qraw[obase + 32 + d0];
    float vlo[8], vhi[8];
    float s = 0.f;
#pragma unroll
    for (int u = 0; u < 8; ++u) {
      vlo[u] = bf2f((u16)xlo[u]);
      vhi[u] = bf2f((u16)xhi[u]);
      s += vlo[u] + vhi[u];
    }
    s += __shfl_xor(s, 1); s += __shfl_xor(s, 2);
    const float mean = s * (1.f / 64.f);
    float vs = 0.f;
#pragma unroll
    for (int u = 0; u < 8; ++u) {
      vlo[u] -= mean; vhi[u] -= mean;
      vs += vlo[u] * vlo[u] + vhi[u] * vhi[u];
    }
    vs += __shfl_xor(vs, 1); vs += __shfl_xor(vs, 2);
    const float rstd = 1.f / sqrtf(vs * (1.f / 64.f) + 1e-5f);
    float olo[8], ohi[8];
#pragma unroll
    for (int u = 0; u < 8; ++u) {
      const float nl_ = vlo[u] * rstd * qg[d0 + u] + qb[d0 + u];
      const float nh_ = vhi[u] * rstd * qg[32 + d0 + u] + qb[32 + d0 + u];
      olo[u] = nl_ * cs_lo[u] - nh_ * sn_lo[u];
      ohi[u] = nh_ * cs_hi[u] + nl_ * sn_hi[u];
    }
    u32x4 plo, phi;
#pragma unroll
    for (int u = 0; u < 4; ++u) {
      plo[u] = cvt_pk_bf16(olo[2 * u], olo[2 * u + 1]);
      phi[u] = cvt_pk_bf16(ohi[2 * u], ohi[2 * u + 1]);
    }
    *(u32x4*)&Q[obase + d0] = plo;
    *(u32x4*)&Q[obase + 32 + d0] = phi;
  }

  // ---- K phase ----
  {
    const short8 xlo = *(const short8*)&Kraw[obase + d0];
    const short8 xhi = *(const short8*)&Kraw[obase + 32 + d0];
    float vlo[8], vhi[8];
    float s = 0.f;
#pragma unroll
    for (int u = 0; u < 8; ++u) {
      vlo[u] = bf2f((u16)xlo[u]);
      vhi[u] = bf2f((u16)xhi[u]);
      s += vlo[u] + vhi[u];
    }
    s += __shfl_xor(s, 1); s += __shfl_xor(s, 2);
    const float mean = s * (1.f / 64.f);
    float vs = 0.f;
#pragma unroll
    for (int u = 0; u < 8; ++u) {
      vlo[u] -= mean; vhi[u] -= mean;
      vs += vlo[u] * vlo[u] + vhi[u] * vhi[u];
    }
    vs += __shfl_xor(vs, 1); vs += __shfl_xor(vs, 2);
    const float rstd = 1.f / sqrtf(vs * (1.f / 64.f) + 1e-5f);
    float olo[8], ohi[8];
#pragma unroll
    for (int u = 0; u < 8; ++u) {
      const float nl_ = vlo[u] * rstd * kg[d0 + u] + kb[d0 + u];
      const float nh_ = vhi[u] * rstd * kg[32 + d0 + u] + kb[32 + d0 + u];
      olo[u] = nl_ * cs_lo[u] - nh_ * sn_lo[u];
      ohi[u] = nh_ * cs_hi[u] + nl_ * sn_hi[u];
    }
    u32x4 plo, phi;
#pragma unroll
    for (int u = 0; u < 4; ++u) {
      plo[u] = cvt_pk_bf16(olo[2 * u], olo[2 * u + 1]);
      phi[u] = cvt_pk_bf16(ohi[2 * u], ohi[2 * u + 1]);
    }
    *(u32x4*)&Ksw[obase + ((c4 ^ nx) * 8)] = plo;
    *(u32x4*)&Ksw[obase + (((c4 + 4) ^ nx) * 8)] = phi;
  }

  // ---- V phase ----
  {
    const float l1 = pl1[0], l2 = pl2[0];
    const short8 xlo = *(const short8*)&Vraw[obase + d0];
    const short8 xhi = *(const short8*)&Vraw[obase + 32 + d0];
    const long vb = ((long)(bh * 1024 + n)) * 64;
    const float4 r0 = *(const float4*)&vres[vb + d0];
    const float4 r1 = *(const float4*)&vres[vb + d0 + 4];
    const float4 r2 = *(const float4*)&vres[vb + 32 + d0];
    const float4 r3 = *(const float4*)&vres[vb + 32 + d0 + 4];
    const float rl[8] = {r0.x, r0.y, r0.z, r0.w, r1.x, r1.y, r1.z, r1.w};
    const float rh[8] = {r2.x, r2.y, r2.z, r2.w, r3.x, r3.y, r3.z, r3.w};
    u32x4 plo, phi;
#pragma unroll
    for (int u = 0; u < 4; ++u) {
      plo[u] = cvt_pk_bf16(l1 * bf2f((u16)xlo[2 * u]) + l2 * rl[2 * u],
                           l1 * bf2f((u16)xlo[2 * u + 1]) + l2 * rl[2 * u + 1]);
      phi[u] = cvt_pk_bf16(l1 * bf2f((u16)xhi[2 * u]) + l2 * rh[2 * u],
                           l1 * bf2f((u16)xhi[2 * u + 1]) + l2 * rh[2 * u + 1]);
    }
    *(u32x4*)&Vl[tl][d0] = plo;
    *(u32x4*)&Vl[tl][32 + d0] = phi;
  }
  __syncthreads();
  // transpose-write V^T (chunk-swizzled per 64-n tile) — proven tail
#pragma unroll
  for (int i = 0; i < 2; ++i) {
    const int task = i * 256 + t;
    const int dd = task >> 3, cc = task & 7;
    short8 o;
#pragma unroll
    for (int u = 0; u < 8; ++u) o[u] = (short)Vl[cc * 8 + u][dd];
    *(short8*)&VTsw[((long)(bh * 64 + dd)) * 1024 + n0 + ((cc ^ (dd & 7)) * 8)] = o;
  }
}

// -------- flash attention fwd v8: in-register P + KVBLK=128 (round-11) --------
__global__ __launch_bounds__(256, 4)
void attn_fwd8(const u16* __restrict__ Q, const u16* __restrict__ Ksw,
               const u16* __restrict__ VTsw, u16* __restrict__ Out) {
  __shared__ u16 Kl[128 * 64];
  __shared__ u16 Vl[64 * 128];
  const int t = threadIdx.x, w = t >> 6, l = t & 63;
  const int l15 = l & 15, lg = l >> 4;
  const int x7 = l15 & 7;
  const int bh = blockIdx.x, q0 = blockIdx.y * 64;
  const long bo = (long)bh * 65536;
  const bool hihalf = (l & 16) != 0;

  const int qrow = q0 + w * 16 + l15;
  short8 qf[2];
#pragma unroll
  for (int ks = 0; ks < 2; ++ks)
    qf[ks] = *(const short8*)&Q[bo + (long)qrow * 64 + ks * 32 + lg * 8];

  f32x4 acc[4] = {};
  float m_run = -1e30f, l_run = 0.f;

  for (int kb = 0; kb < 8; ++kb) {
    const int kvb = kb * 128;
#pragma unroll
    for (int i = 0; i < 4; ++i) {
      const int idx = i * 256 + t;
      const int krow = idx >> 3, kseg = idx & 7;
      gload_lds16(Ksw + bo + (long)(kvb + krow) * 64 + kseg * 8, (char*)Kl + idx * 16);
      const int vd = idx >> 4, vc = idx & 15;
      gload_lds16(VTsw + bo + (long)vd * 1024 + kvb + vc * 8,
                  (char*)Vl + vd * 256 + vc * 16);
    }
    __syncthreads();
#pragma unroll
    for (int tb = 0; tb < 2; ++tb) {
      f32x4 p[4];
#pragma unroll
      for (int mt = 0; mt < 4; ++mt) {
        f32x4 ps = {};
#pragma unroll
        for (int ks = 0; ks < 2; ++ks) {
          const short8 kf = *(const short8*)&Kl[(tb * 64 + mt * 16 + l15) * 64 +
                                                (((ks * 4 + lg) ^ x7) * 8)];
          ps = __builtin_amdgcn_mfma_f32_16x16x32_bf16(kf, qf[ks], ps, 0, 0, 0);
        }
        p[mt] = ps;
      }
      float mx = p[0][0];
#pragma unroll
      for (int mt = 0; mt < 4; ++mt)
#pragma unroll
        for (int r = 0; r < 4; ++r) mx = fmaxf(mx, p[mt][r]);
      mx = fmaxf(mx, __shfl_xor(mx, 16));
      mx = fmaxf(mx, __shfl_xor(mx, 32));
      const float mnew = fmaxf(m_run, mx * 0.125f);
      const float alpha = __expf(m_run - mnew);
      m_run = mnew;
      float sum = 0.f;
#pragma unroll
      for (int mt = 0; mt < 4; ++mt)
#pragma unroll
        for (int r = 0; r < 4; ++r) {
          const float e = __expf(p[mt][r] * 0.125f - mnew);
          p[mt][r] = e;
          sum += e;
        }
      sum += __shfl_xor(sum, 16);
      sum += __shfl_xor(sum, 32);
      l_run = l_run * alpha + sum;
      uint32_t u0[4], u1[4];
#pragma unroll
      for (int mt = 0; mt < 4; ++mt) {
        u0[mt] = cvt_pk_bf16(p[mt][0], p[mt][1]);
        u1[mt] = cvt_pk_bf16(p[mt][2], p[mt][3]);
      }
#pragma unroll
      for (int mt = 0; mt < 4; ++mt)
#pragma unroll
        for (int r = 0; r < 4; ++r) acc[mt][r] *= alpha;
#pragma unroll
      for (int ks = 0; ks < 2; ++ks) {
        uint32_t X0 = u0[2 * ks], Y0 = u0[2 * ks + 1];
        asm("v_permlane32_swap_b32 %0, %1" : "+v"(X0), "+v"(Y0));
        uint32_t X1 = u1[2 * ks], Y1 = u1[2 * ks + 1];
        asm("v_permlane32_swap_b32 %0, %1" : "+v"(X1), "+v"(Y1));
        const uint32_t Xs0 = (uint32_t)__shfl_xor((int)X0, 16);
        const uint32_t Ys0 = (uint32_t)__shfl_xor((int)Y0, 16);
        const uint32_t Xs1 = (uint32_t)__shfl_xor((int)X1, 16);
        const uint32_t Ys1 = (uint32_t)__shfl_xor((int)Y1, 16);
        u32x4 pv;
        pv[0] = hihalf ? Ys0 : X0;
        pv[1] = hihalf ? Ys1 : X1;
        pv[2] = hihalf ? Y0 : Xs0;
        pv[3] = hihalf ? Y1 : Xs1;
        const short8 pf = __builtin_bit_cast(short8, pv);
#pragma unroll
        for (int mt = 0; mt < 4; ++mt) {
          const short8 vf = *(const short8*)&Vl[(mt * 16 + l15) * 128 + tb * 64 +
                                                (((ks * 4 + lg) ^ x7) * 8)];
          acc[mt] = __builtin_amdgcn_mfma_f32_16x16x32_bf16(vf, pf, acc[mt], 0, 0, 0);
        }
      }
    }
    __syncthreads();
  }
  const int b = bh >> 4, h = bh & 15;
  const float inv = 1.f / l_run;
  const long obase = ((long)(b * 1024 + qrow)) * 1024 + h * 64;
#pragma unroll
  for (int mt = 0; mt < 4; ++mt) {
    const long o = obase + mt * 16 + lg * 4;
    *(uint32_t*)&Out[o] = cvt_pk_bf16(acc[mt][0] * inv, acc[mt][1] * inv);
    *(uint32_t*)&Out[o + 2] = cvt_pk_bf16(acc[mt][2] * inv, acc[mt][3] * inv);
  }
}

extern "C" void kernel_launch(void* const* d_in, const int* in_sizes, int n_in,
                              void* d_out, int out_size, void* d_ws, size_t ws_size,
                              hipStream_t stream) {
  const float* x     = (const float*)d_in[0];
  const float* rope  = (const float*)d_in[1];
  const float* dte   = (const float*)d_in[2];
  const float* vres  = (const float*)d_in[3];
  const float* Wqkv  = (const float*)d_in[4];
  const float* bqkv  = (const float*)d_in[5];
  const float* Wdt   = (const float*)d_in[6];
  const float* bdt   = (const float*)d_in[7];
  const float* qn_g  = (const float*)d_in[8];
  const float* qn_b  = (const float*)d_in[9];
  const float* kn_g  = (const float*)d_in[10];
  const float* kn_b  = (const float*)d_in[11];
  const float* l1    = (const float*)d_in[12];
  const float* l2    = (const float*)d_in[13];
  const float* Wproj = (const float*)d_in[14];
  const float* bproj = (const float*)d_in[15];
  float* out = (float*)d_out;

  char* ws = (char*)d_ws;
  u16*   A_cat = (u16*)(ws);                    // [4096,2048] bf16
  u16*   W_cat = (u16*)(ws + 16777216);         // [3072,2048] bf16
  u16*   Wp    = (u16*)(ws + 29360128);         // [1024,1024] bf16
  u16*   Qraw  = (u16*)(ws + 31457280);         // [64,1024,64] bf16 head-major
  u16*   Kraw  = (u16*)(ws + 39845888);
  u16*   Vraw  = (u16*)(ws + 48234496);
  u16*   Qb    = (u16*)(ws + 56623104);         // [64,1024,64] bf16
  u16*   Ksw   = (u16*)(ws + 65011712);         // swizzled K
  u16*   VTsw  = (u16*)(ws + 73400320);         // swizzled V^T
  u16*   AO    = (u16*)(ws + 81788928);         // [4096,1024] bf16
  // total ws usage: 90,177,536 bytes

  cvt_all<<<2048, 256, 0, stream>>>(x, dte, Wqkv, Wdt, Wproj, A_cat, W_cat, Wp);
  gemm_qkv_hm<<<dim3(32, 24), 256, 0, stream>>>(A_cat, W_cat, bqkv, bdt,
                                                Qraw, Kraw, Vraw, 4096, 3072, 2048);
  fuse_qkv4<<<dim3(64, 16), 256, 0, stream>>>(Qraw, Kraw, Vraw, vres, rope,
                                              qn_g, qn_b, kn_g, kn_b, l1, l2,
                                              Qb, Ksw, VTsw);
  attn_fwd8<<<dim3(64, 16), 256, 0, stream>>>(Qb, Ksw, VTsw, AO);
  gemm_bt64<<<dim3(64, 8), 256, 0, stream>>>(AO, Wp, out, bproj, 4096, 1024, 1024);
}